// Round 1
// baseline (266.502 us; speedup 1.0000x reference)
//
#include <hip/hip_runtime.h>

#define TAB_CLASSES 21
#define TAB_KEEP    20
#define F0_CLASSES  45
#define F0_KEEP     44
#define STRINGS     6

// ws layout (unsigned int): [0]=tabTP [1]=tabFP [2]=tabFN [3]=f0TP [4]=f0FP [5]=f0FN

__device__ __forceinline__ void block_reduce_and_commit(
    unsigned int tp, unsigned int fp, unsigned int fn,
    unsigned int* red, unsigned int* ws, int base)
{
    if (threadIdx.x < 3) red[threadIdx.x] = 0;
    __syncthreads();
    atomicAdd(&red[0], tp);
    atomicAdd(&red[1], fp);
    atomicAdd(&red[2], fn);
    __syncthreads();
    if (threadIdx.x == 0) {
        atomicAdd(&ws[base + 0], red[0]);
        atomicAdd(&ws[base + 1], red[1]);
        atomicAdd(&ws[base + 2], red[2]);
    }
}

// Generic pattern: each block handles tiles of 256 rows, each row has NC classes.
// Stage pred tile -> argmax -> stage gt tile -> argmax -> update counters.

__global__ __launch_bounds__(256) void tab_count_kernel(
    const float* __restrict__ pred, const float* __restrict__ gt,
    const int* __restrict__ gtlen_p, unsigned int* __restrict__ ws,
    int ncells)
{
    __shared__ float tile[256 * TAB_CLASSES];
    __shared__ unsigned int red[3];
    const int tid = threadIdx.x;
    const int gtlen = *gtlen_p;
    const int nfloats = 256 * TAB_CLASSES;

    unsigned int tp = 0, fp = 0, fn = 0;
    const int ntiles = (ncells + 255) / 256;

    for (int ti = blockIdx.x; ti < ntiles; ti += gridDim.x) {
        const int c0 = ti * 256;
        const bool full = (c0 + 256 <= ncells);
        const bool valid = (c0 + tid) < ncells;

        // ---- stage pred tile (coalesced) ----
        if (full) {
            const float4* src = reinterpret_cast<const float4*>(pred + (size_t)c0 * TAB_CLASSES);
            float4* dst = reinterpret_cast<float4*>(tile);
            #pragma unroll
            for (int i = 0; i < nfloats / 4 / 256 + 1; ++i) {
                int idx = tid + i * 256;
                if (idx < nfloats / 4) dst[idx] = src[idx];
            }
        } else {
            const size_t base = (size_t)c0 * TAB_CLASSES;
            const size_t total = (size_t)ncells * TAB_CLASSES;
            for (int i = tid; i < nfloats; i += 256)
                tile[i] = (base + i < total) ? pred[base + i] : 0.0f;
        }
        __syncthreads();

        int pidx = 0;
        {
            float best = -1e30f;
            #pragma unroll
            for (int f = 0; f < TAB_CLASSES; ++f) {
                float v = tile[tid * TAB_CLASSES + f];
                if (v > best) { best = v; pidx = f; }
            }
        }
        __syncthreads();

        // ---- stage gt tile ----
        if (full) {
            const float4* src = reinterpret_cast<const float4*>(gt + (size_t)c0 * TAB_CLASSES);
            float4* dst = reinterpret_cast<float4*>(tile);
            #pragma unroll
            for (int i = 0; i < nfloats / 4 / 256 + 1; ++i) {
                int idx = tid + i * 256;
                if (idx < nfloats / 4) dst[idx] = src[idx];
            }
        } else {
            const size_t base = (size_t)c0 * TAB_CLASSES;
            const size_t total = (size_t)ncells * TAB_CLASSES;
            for (int i = tid; i < nfloats; i += 256)
                tile[i] = (base + i < total) ? gt[base + i] : 0.0f;
        }
        __syncthreads();

        int gidx = 0;
        {
            float best = -1e30f;
            #pragma unroll
            for (int f = 0; f < TAB_CLASSES; ++f) {
                float v = tile[tid * TAB_CLASSES + f];
                if (v > best) { best = v; gidx = f; }
            }
        }

        if (valid) {
            const int t = (c0 + tid) / STRINGS;
            const bool predP = (t < gtlen) && (pidx < TAB_KEEP);
            const bool gtP   = (gidx < TAB_KEEP);
            const bool eq    = (pidx == gidx);
            tp += (predP && gtP && eq) ? 1u : 0u;
            fp += (predP && !(gtP && eq)) ? 1u : 0u;
            fn += (gtP && !(predP && eq)) ? 1u : 0u;
        }
        __syncthreads();   // protect tile before next iteration's staging
    }

    block_reduce_and_commit(tp, fp, fn, red, ws, 0);
}

__global__ __launch_bounds__(256) void f0_count_kernel(
    const float* __restrict__ pred, const float* __restrict__ gt,
    const int* __restrict__ gtlen_p, unsigned int* __restrict__ ws,
    int nrows)
{
    __shared__ float tile[256 * F0_CLASSES];
    __shared__ unsigned int red[3];
    const int tid = threadIdx.x;
    const int gtlen = *gtlen_p;
    const int nfloats = 256 * F0_CLASSES;

    unsigned int tp = 0, fp = 0, fn = 0;
    const int ntiles = (nrows + 255) / 256;

    for (int ti = blockIdx.x; ti < ntiles; ti += gridDim.x) {
        const int r0 = ti * 256;
        const bool full = (r0 + 256 <= nrows);
        const bool valid = (r0 + tid) < nrows;

        if (full) {
            const float4* src = reinterpret_cast<const float4*>(pred + (size_t)r0 * F0_CLASSES);
            float4* dst = reinterpret_cast<float4*>(tile);
            #pragma unroll
            for (int i = 0; i < nfloats / 4 / 256 + 1; ++i) {
                int idx = tid + i * 256;
                if (idx < nfloats / 4) dst[idx] = src[idx];
            }
        } else {
            const size_t base = (size_t)r0 * F0_CLASSES;
            const size_t total = (size_t)nrows * F0_CLASSES;
            for (int i = tid; i < nfloats; i += 256)
                tile[i] = (base + i < total) ? pred[base + i] : 0.0f;
        }
        __syncthreads();

        int pidx = 0;
        {
            float best = -1e30f;
            #pragma unroll
            for (int p = 0; p < F0_CLASSES; ++p) {
                float v = tile[tid * F0_CLASSES + p];
                if (v > best) { best = v; pidx = p; }
            }
        }
        __syncthreads();

        if (full) {
            const float4* src = reinterpret_cast<const float4*>(gt + (size_t)r0 * F0_CLASSES);
            float4* dst = reinterpret_cast<float4*>(tile);
            #pragma unroll
            for (int i = 0; i < nfloats / 4 / 256 + 1; ++i) {
                int idx = tid + i * 256;
                if (idx < nfloats / 4) dst[idx] = src[idx];
            }
        } else {
            const size_t base = (size_t)r0 * F0_CLASSES;
            const size_t total = (size_t)nrows * F0_CLASSES;
            for (int i = tid; i < nfloats; i += 256)
                tile[i] = (base + i < total) ? gt[base + i] : 0.0f;
        }
        __syncthreads();

        int gidx = 0;
        {
            float best = -1e30f;
            #pragma unroll
            for (int p = 0; p < F0_CLASSES; ++p) {
                float v = tile[tid * F0_CLASSES + p];
                if (v > best) { best = v; gidx = p; }
            }
        }

        if (valid) {
            const int t = r0 + tid;
            const bool predP = (t < gtlen) && (pidx < F0_KEEP);
            const bool gtP   = (gidx < F0_KEEP);
            const bool eq    = (pidx == gidx);
            tp += (predP && gtP && eq) ? 1u : 0u;
            fp += (predP && !(gtP && eq)) ? 1u : 0u;
            fn += (gtP && !(predP && eq)) ? 1u : 0u;
        }
        __syncthreads();
    }

    block_reduce_and_commit(tp, fp, fn, red, ws, 3);
}

__device__ __forceinline__ void write_scores(
    float TP, float TN, float FP, float FN, float* o)
{
    // matches jnp.nan_to_num(x/y) : 0/0 -> 0
    float dp = TP + FP;
    float prec = (dp != 0.0f) ? TP / dp : 0.0f;
    float dr = TP + FN;
    float rec = (dr != 0.0f) ? TP / dr : 0.0f;
    float df = prec + rec;
    float f1 = (df != 0.0f) ? 2.0f * prec * rec / df : 0.0f;
    float acc = (TP + TN) / (TP + FN + TN + FP);
    o[0] = prec; o[1] = rec; o[2] = f1; o[3] = acc;
}

__global__ void score_kernel(const unsigned int* __restrict__ ws,
                             float* __restrict__ out,
                             unsigned long long tabTotal,
                             unsigned long long f0Total)
{
    if (blockIdx.x == 0 && threadIdx.x == 0) {
        unsigned long long ttp = ws[0], tfp = ws[1], tfn = ws[2];
        unsigned long long ftp = ws[3], ffp = ws[4], ffn = ws[5];
        unsigned long long ttn = tabTotal - ttp - tfp - tfn;
        unsigned long long ftn = f0Total - ftp - ffp - ffn;
        write_scores((float)ttp, (float)ttn, (float)tfp, (float)tfn, out);
        write_scores((float)ftp, (float)ftn, (float)ffp, (float)ffn, out + 4);
    }
}

extern "C" void kernel_launch(void* const* d_in, const int* in_sizes, int n_in,
                              void* d_out, int out_size, void* d_ws, size_t ws_size,
                              hipStream_t stream) {
    const float* tab_pred = (const float*)d_in[0];
    const float* F0_pred  = (const float*)d_in[1];
    const float* tab_gt   = (const float*)d_in[2];
    const float* F0_gt    = (const float*)d_in[3];
    const int*   gtlen    = (const int*)d_in[4];

    const int T = in_sizes[1] / F0_CLASSES;         // 500000
    const int ncells = T * STRINGS;                 // 3,000,000

    unsigned int* ws = (unsigned int*)d_ws;
    hipMemsetAsync(d_ws, 0, 8 * sizeof(unsigned int), stream);

    const int tabTiles = (ncells + 255) / 256;
    const int f0Tiles  = (T + 255) / 256;
    const int tabGrid = tabTiles < 2048 ? tabTiles : 2048;
    const int f0Grid  = f0Tiles  < 2048 ? f0Tiles  : 2048;

    tab_count_kernel<<<tabGrid, 256, 0, stream>>>(tab_pred, tab_gt, gtlen, ws, ncells);
    f0_count_kernel<<<f0Grid, 256, 0, stream>>>(F0_pred, F0_gt, gtlen, ws, T);

    score_kernel<<<1, 1, 0, stream>>>(
        ws, (float*)d_out,
        (unsigned long long)ncells * TAB_KEEP,
        (unsigned long long)T * F0_KEEP);
}

// Round 2
// 248.746 us; speedup vs baseline: 1.0714x; 1.0714x over previous
//
#include <hip/hip_runtime.h>

#define STRINGS 6

// Each thread handles 4 consecutive rows of an [N][NC] f32 matrix.
// 4*NC floats = NC float4s, and the byte base g*16*NC is 16B-aligned.
template<int NC>
__device__ __forceinline__ void argmax_rows4(const float* __restrict__ arr, int g, int idx[4]) {
    const float4* p = reinterpret_cast<const float4*>(arr) + (size_t)g * NC;
    float best[4] = {-3.4e38f, -3.4e38f, -3.4e38f, -3.4e38f};
    idx[0] = idx[1] = idx[2] = idx[3] = 0;
    #pragma unroll
    for (int q = 0; q < NC; ++q) {
        float4 v = p[q];
        float xs[4] = {v.x, v.y, v.z, v.w};
        #pragma unroll
        for (int j = 0; j < 4; ++j) {
            const int e = q * 4 + j;      // compile-time
            const int r = e / NC;         // compile-time
            const int c = e - r * NC;     // compile-time
            if (xs[j] > best[r]) { best[r] = xs[j]; idx[r] = c; }
        }
    }
}

// ws layout (u32): [0]=tabTP [1]=tabFP [2]=tabFN [3]=f0TP [4]=f0FP [5]=f0FN
__global__ __launch_bounds__(256) void count_kernel(
    const float* __restrict__ tab_pred, const float* __restrict__ tab_gt,
    const float* __restrict__ f0_pred,  const float* __restrict__ f0_gt,
    const int* __restrict__ gtlen_p, unsigned int* __restrict__ ws,
    int tabBlocks, int tabGroups, int f0Groups)
{
    __shared__ unsigned int red[3];
    const int tid = threadIdx.x;
    if (tid < 3) red[tid] = 0;
    __syncthreads();

    const int gtlen = *gtlen_p;
    unsigned int tp = 0, fp = 0, fn = 0;
    int base;

    if (blockIdx.x < tabBlocks) {
        base = 0;
        const int g = blockIdx.x * 256 + tid;
        if (g < tabGroups) {
            int pidx[4], gidx[4];
            argmax_rows4<21>(tab_pred, g, pidx);
            argmax_rows4<21>(tab_gt,   g, gidx);
            #pragma unroll
            for (int k = 0; k < 4; ++k) {
                const int cell = g * 4 + k;
                const int t = cell / STRINGS;
                const bool predP = (t < gtlen) && (pidx[k] < 20);
                const bool gtP   = (gidx[k] < 20);
                const bool eq    = (pidx[k] == gidx[k]);
                tp += (predP && gtP && eq) ? 1u : 0u;
                fp += (predP && !(gtP && eq)) ? 1u : 0u;
                fn += (gtP && !(predP && eq)) ? 1u : 0u;
            }
        }
    } else {
        base = 3;
        const int g = (blockIdx.x - tabBlocks) * 256 + tid;
        if (g < f0Groups) {
            int pidx[4], gidx[4];
            argmax_rows4<45>(f0_pred, g, pidx);
            argmax_rows4<45>(f0_gt,   g, gidx);
            #pragma unroll
            for (int k = 0; k < 4; ++k) {
                const int t = g * 4 + k;
                const bool predP = (t < gtlen) && (pidx[k] < 44);
                const bool gtP   = (gidx[k] < 44);
                const bool eq    = (pidx[k] == gidx[k]);
                tp += (predP && gtP && eq) ? 1u : 0u;
                fp += (predP && !(gtP && eq)) ? 1u : 0u;
                fn += (gtP && !(predP && eq)) ? 1u : 0u;
            }
        }
    }

    atomicAdd(&red[0], tp);
    atomicAdd(&red[1], fp);
    atomicAdd(&red[2], fn);
    __syncthreads();
    if (tid == 0) {
        atomicAdd(&ws[base + 0], red[0]);
        atomicAdd(&ws[base + 1], red[1]);
        atomicAdd(&ws[base + 2], red[2]);
    }
}

__device__ __forceinline__ void write_scores(
    float TP, float TN, float FP, float FN, float* o)
{
    // matches jnp.nan_to_num(x/y): 0/0 -> 0
    float dp = TP + FP;
    float prec = (dp != 0.0f) ? TP / dp : 0.0f;
    float dr = TP + FN;
    float rec = (dr != 0.0f) ? TP / dr : 0.0f;
    float df = prec + rec;
    float f1 = (df != 0.0f) ? 2.0f * prec * rec / df : 0.0f;
    float acc = (TP + TN) / (TP + FN + TN + FP);
    o[0] = prec; o[1] = rec; o[2] = f1; o[3] = acc;
}

__global__ void score_kernel(const unsigned int* __restrict__ ws,
                             float* __restrict__ out,
                             unsigned long long tabTotal,
                             unsigned long long f0Total)
{
    if (blockIdx.x == 0 && threadIdx.x == 0) {
        unsigned long long ttp = ws[0], tfp = ws[1], tfn = ws[2];
        unsigned long long ftp = ws[3], ffp = ws[4], ffn = ws[5];
        unsigned long long ttn = tabTotal - ttp - tfp - tfn;
        unsigned long long ftn = f0Total - ftp - ffp - ffn;
        write_scores((float)ttp, (float)ttn, (float)tfp, (float)tfn, out);
        write_scores((float)ftp, (float)ftn, (float)ffp, (float)ffn, out + 4);
    }
}

extern "C" void kernel_launch(void* const* d_in, const int* in_sizes, int n_in,
                              void* d_out, int out_size, void* d_ws, size_t ws_size,
                              hipStream_t stream) {
    const float* tab_pred = (const float*)d_in[0];
    const float* F0_pred  = (const float*)d_in[1];
    const float* tab_gt   = (const float*)d_in[2];
    const float* F0_gt    = (const float*)d_in[3];
    const int*   gtlen    = (const int*)d_in[4];

    const int T = in_sizes[1] / 45;        // 500000
    const int ncells = T * STRINGS;        // 3,000,000 (divisible by 4)

    const int tabGroups = ncells / 4;      // 750000
    const int f0Groups  = T / 4;           // 125000
    const int tabBlocks = (tabGroups + 255) / 256;   // 2930
    const int f0Blocks  = (f0Groups + 255) / 256;    // 489

    unsigned int* ws = (unsigned int*)d_ws;
    hipMemsetAsync(d_ws, 0, 8 * sizeof(unsigned int), stream);

    count_kernel<<<tabBlocks + f0Blocks, 256, 0, stream>>>(
        tab_pred, tab_gt, F0_pred, F0_gt, gtlen, ws,
        tabBlocks, tabGroups, f0Groups);

    score_kernel<<<1, 1, 0, stream>>>(
        ws, (float*)d_out,
        (unsigned long long)ncells * 20,
        (unsigned long long)T * 44);
}